// Round 6
// baseline (177.588 us; speedup 1.0000x reference)
//
#include <hip/hip_runtime.h>
#include <hip/hip_bf16.h>
#include <hip/hip_fp16.h>
#include <math.h>

#define NSPH 7
#define NRAD 6
#define NJ 42
#define ROWH 44           // LDS row stride in halves (88 B) -> 22528 B/block
#define BLK 256

typedef float v2 __attribute__((ext_vector_type(2)));

struct KC {
  float zf[NJ];     // bessel zeros
  float izf[NJ];    // 1/z
  float nyf[NJ];    // NORM * Y_NORM
  float sc5[7];     // series coeffs for j5
  float sc6[7];     // series coeffs for j6
};

// ---------------- fused kernel ------------------------------------------------
__global__ void __launch_bounds__(BLK, 4) k_fused(const float* __restrict__ d,
                                                  const float* __restrict__ ang,
                                                  const int* __restrict__ idx,
                                                  float* __restrict__ out,
                                                  int T, KC C) {
  __shared__ __half sv[BLK * ROWH];   // 22528 B
  const int tid = threadIdx.x;
  const int t0 = blockIdx.x * BLK;
  const int t = t0 + tid;

  if (t < T) {
    const int e = __builtin_nontemporal_load(idx + t);
    const float an = __builtin_nontemporal_load(ang + t);
    const float dv = d[e];                         // 4 MB: L2/L3-resident gather

    const float x = dv * 0.2f;
    const float invx = __builtin_amdgcn_rcpf(x);   // 1-ulp; amplification <= ~200
    const float x2 = x * x;
    const float x5 = x2 * x2 * x;
    float env = invx + x5 * fmaf(x, fmaf(x, -21.0f, 48.0f), -28.0f);
    if (x >= 1.0f) env = 0.0f;

    // Legendre P_l(cos an) * env
    const float cth = __cosf(an);
    float mP[NSPH];
    {
      float p0 = 1.f, p1 = cth;
      mP[0] = env; mP[1] = env * cth;
      const float rl[5] = {1.f/2.f, 1.f/3.f, 1.f/4.f, 1.f/5.f, 1.f/6.f};
      #pragma unroll
      for (int l = 2; l < NSPH; ++l) {
        float pn = (fmaf((float)(2*l-1) * cth, p1, -(float)(l-1) * p0)) * rl[l-2];
        mP[l] = env * pn;
        p0 = p1; p1 = pn;
      }
    }

    __half* row = sv + tid * ROWH;

    // ---- l = 0..4 : packed-f32 pairs, HW trig, upward recurrence -------------
    #pragma unroll
    for (int l = 0; l < 5; ++l) {
      #pragma unroll
      for (int p = 0; p < 3; ++p) {
        const int i = l * NRAD + 2 * p;
        v2 z    = {C.zf[i],  C.zf[i+1]};
        v2 iz   = {C.izf[i], C.izf[i+1]};
        v2 ny   = {C.nyf[i], C.nyf[i+1]};
        v2 a    = z * x;
        v2 s;  s.x = __sinf(a.x);  s.y = __sinf(a.y);
        v2 inva = iz * invx;
        v2 j0   = s * inva;
        v2 jl;
        if (l == 0) {
          jl = j0;
        } else {
          v2 c;  c.x = __cosf(a.x);  c.y = __cosf(a.y);
          v2 j1 = (j0 - c) * inva;
          #pragma unroll
          for (int m = 2; m <= l; ++m) {
            v2 jn_ = ((float)(2*m-1) * inva) * j1 - j0;
            j0 = j1; j1 = jn_;
          }
          jl = j1;
        }
        v2 jv = (ny * jl) * mP[l];
        *(__half2*)(row + i) = __float22half2_rn((float2){jv.x, jv.y});
      }
    }

    // ---- l = 5,6 : packed-f32 stability split --------------------------------
    //   a >= 4: upward recurrence (amplification <= ~10)
    //   a <  4: 7-term power series (stable, rel err ~1e-7)
    #pragma unroll
    for (int l = 5; l < NSPH; ++l) {
      const float* sc = (l == 5) ? C.sc5 : C.sc6;
      #pragma unroll
      for (int p = 0; p < 3; ++p) {
        const int i = l * NRAD + 2 * p;
        v2 z    = {C.zf[i],  C.zf[i+1]};
        v2 iz   = {C.izf[i], C.izf[i+1]};
        v2 ny   = {C.nyf[i], C.nyf[i+1]};
        v2 a    = z * x;
        v2 s;  s.x = __sinf(a.x);  s.y = __sinf(a.y);
        v2 c;  c.x = __cosf(a.x);  c.y = __cosf(a.y);
        v2 inva = iz * invx;
        v2 j0   = s * inva;
        v2 j1   = (j0 - c) * inva;
        #pragma unroll
        for (int m = 2; m <= l; ++m) {
          v2 jn_ = ((float)(2*m-1) * inva) * j1 - j0;
          j0 = j1; j1 = jn_;
        }
        v2 u  = a * a;
        v2 pp = u * sc[6] + sc[5];
        pp = u * pp + sc[4];
        pp = u * pp + sc[3];
        pp = u * pp + sc[2];
        pp = u * pp + sc[1];
        pp = u * pp + sc[0];
        v2 u2 = u * u;
        v2 al = (l == 5) ? (u2 * a) : (u2 * u);
        v2 jser = al * pp;
        v2 jl;
        jl.x = (a.x < 4.0f) ? jser.x : j1.x;
        jl.y = (a.y < 4.0f) ? jser.y : j1.y;
        v2 jv = (ny * jl) * mP[l];
        *(__half2*)(row + i) = __float22half2_rn((float2){jv.x, jv.y});
      }
    }
  }
  __syncthreads();

  // ---- coalesced output: LDS(fp16) -> global f32, plain float2 stores --------
  v2* obase = (v2*)(out + (size_t)t0 * NJ);
  #pragma unroll
  for (int k = 0; k < 21; ++k) {
    unsigned w = k * BLK + tid;
    unsigned tl = w / 21u;
    unsigned jp = w - tl * 21u;
    if ((int)(t0 + tl) < T) {
      __half2 hh = *(const __half2*)(sv + tl * ROWH + 2 * jp);
      float2 r = __half22float2(hh);
      obase[w] = (v2){r.x, r.y};
    }
  }
}

// ---------------- host: bessel zeros / norms (f64, deterministic) -------------
static double jn_host(int l, double x) {
  double j0 = sin(x) / x;
  if (l == 0) return j0;
  double j1 = sin(x) / (x * x) - cos(x) / x;
  for (int i = 2; i <= l; ++i) {
    double jn_ = (2 * i - 1) / x * j1 - j0;
    j0 = j1; j1 = jn_;
  }
  return j1;
}

extern "C" void kernel_launch(void* const* d_in, const int* in_sizes, int n_in,
                              void* d_out, int out_size, void* d_ws, size_t ws_size,
                              hipStream_t stream) {
  const float* d   = (const float*)d_in[0];
  const float* ang = (const float*)d_in[1];
  const int*   idx = (const int*)d_in[2];
  float* out = (float*)d_out;
  const int T = in_sizes[1];

  KC C;
  {
    const double PI = 3.14159265358979323846;
    double zeros[NSPH][NRAD];
    double prev[NSPH + NRAD - 1];
    int np_ = NSPH + NRAD - 1;
    for (int i = 0; i < np_; ++i) prev[i] = (i + 1) * PI;
    for (int j = 0; j < NRAD; ++j) zeros[0][j] = prev[j];
    for (int l = 1; l < NSPH; ++l) {
      int nc = np_ - 1;
      double cur[NSPH + NRAD - 1];
      for (int i = 0; i < nc; ++i) {
        double a = prev[i], b = prev[i + 1];
        double fa = jn_host(l, a);
        for (int it = 0; it < 80; ++it) {
          double m = 0.5 * (a + b);
          double fm = jn_host(l, m);
          if ((fm > 0.0) == (fa > 0.0)) { a = m; fa = fm; } else { b = m; }
        }
        cur[i] = 0.5 * (a + b);
      }
      for (int i = 0; i < nc; ++i) prev[i] = cur[i];
      np_ = nc;
      for (int j = 0; j < NRAD; ++j) zeros[l][j] = prev[j];
    }
    for (int l = 0; l < NSPH; ++l) {
      double yn = sqrt((2.0 * l + 1.0) / (4.0 * PI));
      for (int n = 0; n < NRAD; ++n) {
        int i = l * NRAD + n;
        double z = zeros[l][n];
        C.zf[i]  = (float)z;
        C.izf[i] = (float)(1.0 / z);
        C.nyf[i] = (float)(sqrt(2.0) / fabs(jn_host(l + 1, z)) * yn);
      }
    }
    // series: j_l(a) = a^l * sum_k c_k (a^2)^k ; c_0 = 1/(2l+1)!!,
    // c_k = -c_{k-1} / (2k*(2l+2k+1))
    for (int l = 5; l <= 6; ++l) {
      double dfact = 1.0;
      for (int m = 2 * l + 1; m > 1; m -= 2) dfact *= m;
      double ck = 1.0 / dfact;
      float* sc = (l == 5) ? C.sc5 : C.sc6;
      sc[0] = (float)ck;
      for (int k = 1; k < 7; ++k) {
        ck = -ck / (2.0 * k * (2 * l + 2 * k + 1));
        sc[k] = (float)ck;
      }
    }
  }

  k_fused<<<(T + BLK - 1) / BLK, BLK, 0, stream>>>(d, ang, idx, out, T, C);
}

// Round 7
// 165.389 us; speedup vs baseline: 1.0738x; 1.0738x over previous
//
#include <hip/hip_runtime.h>
#include <hip/hip_bf16.h>
#include <hip/hip_fp16.h>
#include <math.h>

#define NSPH 7
#define NRAD 6
#define NJ 42
#define BLK 256

typedef float v2 __attribute__((ext_vector_type(2)));
typedef float v4 __attribute__((ext_vector_type(4)));

struct KC {
  float zf[NJ];     // bessel zeros
  float izf[NJ];    // 1/z
  float nyf[NJ];    // NORM * Y_NORM
  float sc5[7];     // series coeffs for j5
  float sc6[7];     // series coeffs for j6
};

// ---------------- fused kernel ------------------------------------------------
__global__ void __launch_bounds__(BLK, 4) k_fused(const float* __restrict__ d,
                                                  const float* __restrict__ ang,
                                                  const int* __restrict__ idx,
                                                  float* __restrict__ out,
                                                  int T, KC C) {
  __shared__ __half sv[BLK * NJ];    // unpadded fp16 image of block output: 21504 B
  const int tid = threadIdx.x;
  const int t0 = blockIdx.x * BLK;
  const int t = t0 + tid;

  if (t < T) {
    const int e = __builtin_nontemporal_load(idx + t);
    const float an = __builtin_nontemporal_load(ang + t);
    const float dv = d[e];                         // 4 MB: L2-resident gather

    const float x = dv * 0.2f;
    const float invx = __builtin_amdgcn_rcpf(x);   // 1-ulp; amplification <= ~200
    const float x2 = x * x;
    const float x5 = x2 * x2 * x;
    float env = invx + x5 * fmaf(x, fmaf(x, -21.0f, 48.0f), -28.0f);
    if (x >= 1.0f) env = 0.0f;

    // Legendre P_l(cos an) * env
    const float cth = __cosf(an);
    float mP[NSPH];
    {
      float p0 = 1.f, p1 = cth;
      mP[0] = env; mP[1] = env * cth;
      const float rl[5] = {1.f/2.f, 1.f/3.f, 1.f/4.f, 1.f/5.f, 1.f/6.f};
      #pragma unroll
      for (int l = 2; l < NSPH; ++l) {
        float pn = (fmaf((float)(2*l-1) * cth, p1, -(float)(l-1) * p0)) * rl[l-2];
        mP[l] = env * pn;
        p0 = p1; p1 = pn;
      }
    }

    __half* row = sv + tid * NJ;   // byte offset 84*tid: bank (21*tid+j)%32, 21 odd -> 2-way max

    // ---- l = 0..4 : packed-f32 pairs, HW trig, upward recurrence -------------
    #pragma unroll
    for (int l = 0; l < 5; ++l) {
      #pragma unroll
      for (int p = 0; p < 3; ++p) {
        const int i = l * NRAD + 2 * p;
        v2 z    = {C.zf[i],  C.zf[i+1]};
        v2 iz   = {C.izf[i], C.izf[i+1]};
        v2 ny   = {C.nyf[i], C.nyf[i+1]};
        v2 a    = z * x;
        v2 s;  s.x = __sinf(a.x);  s.y = __sinf(a.y);
        v2 inva = iz * invx;
        v2 j0   = s * inva;
        v2 jl;
        if (l == 0) {
          jl = j0;
        } else {
          v2 c;  c.x = __cosf(a.x);  c.y = __cosf(a.y);
          v2 j1 = (j0 - c) * inva;
          #pragma unroll
          for (int m = 2; m <= l; ++m) {
            v2 jn_ = ((float)(2*m-1) * inva) * j1 - j0;
            j0 = j1; j1 = jn_;
          }
          jl = j1;
        }
        v2 jv = (ny * jl) * mP[l];
        *(__half2*)(row + i) = __float22half2_rn((float2){jv.x, jv.y});
      }
    }

    // ---- l = 5,6 : packed-f32 stability split --------------------------------
    //   a >= 4: upward recurrence (amplification <= ~10)
    //   a <  4: 7-term power series (stable, rel err ~1e-7)
    #pragma unroll
    for (int l = 5; l < NSPH; ++l) {
      const float* sc = (l == 5) ? C.sc5 : C.sc6;
      #pragma unroll
      for (int p = 0; p < 3; ++p) {
        const int i = l * NRAD + 2 * p;
        v2 z    = {C.zf[i],  C.zf[i+1]};
        v2 iz   = {C.izf[i], C.izf[i+1]};
        v2 ny   = {C.nyf[i], C.nyf[i+1]};
        v2 a    = z * x;
        v2 s;  s.x = __sinf(a.x);  s.y = __sinf(a.y);
        v2 c;  c.x = __cosf(a.x);  c.y = __cosf(a.y);
        v2 inva = iz * invx;
        v2 j0   = s * inva;
        v2 j1   = (j0 - c) * inva;
        #pragma unroll
        for (int m = 2; m <= l; ++m) {
          v2 jn_ = ((float)(2*m-1) * inva) * j1 - j0;
          j0 = j1; j1 = jn_;
        }
        v2 u  = a * a;
        v2 pp = u * sc[6] + sc[5];
        pp = u * pp + sc[4];
        pp = u * pp + sc[3];
        pp = u * pp + sc[2];
        pp = u * pp + sc[1];
        pp = u * pp + sc[0];
        v2 u2 = u * u;
        v2 al = (l == 5) ? (u2 * a) : (u2 * u);
        v2 jser = al * pp;
        v2 jl;
        jl.x = (a.x < 4.0f) ? jser.x : j1.x;
        jl.y = (a.y < 4.0f) ? jser.y : j1.y;
        v2 jv = (ny * jl) * mP[l];
        *(__half2*)(row + i) = __float22half2_rn((float2){jv.x, jv.y});
      }
    }
  }
  __syncthreads();

  // ---- output: LDS image -> global, dwordx4 nt stores ------------------------
  const int nwords = (((T - t0) < BLK ? (T - t0) : BLK)) * NJ;  // f32 words
  const int nv4 = nwords >> 2;                                  // full float4s (2688 if full)
  float* ob = out + (size_t)t0 * NJ;
  #pragma unroll
  for (int k = 0; k < 11; ++k) {
    int w4 = k * BLK + tid;
    if (w4 < nv4) {
      uint2 hh = *(const uint2*)((const unsigned char*)sv + 8u * (unsigned)w4);
      float2 r0 = __half22float2(*(__half2*)&hh.x);
      float2 r1 = __half22float2(*(__half2*)&hh.y);
      v4 val = {r0.x, r0.y, r1.x, r1.y};
      __builtin_nontemporal_store(val, (v4*)(ob + 4 * w4));
    }
  }
  {  // residual words (only when T-t0 makes nwords non-multiple-of-4)
    int rem = nwords - (nv4 << 2);
    if (tid < rem) {
      int wd = (nv4 << 2) + tid;
      float r = __half2float(sv[wd]);
      __builtin_nontemporal_store(r, ob + wd);
    }
  }
}

// ---------------- host: bessel zeros / norms (f64, deterministic) -------------
static double jn_host(int l, double x) {
  double j0 = sin(x) / x;
  if (l == 0) return j0;
  double j1 = sin(x) / (x * x) - cos(x) / x;
  for (int i = 2; i <= l; ++i) {
    double jn_ = (2 * i - 1) / x * j1 - j0;
    j0 = j1; j1 = jn_;
  }
  return j1;
}

extern "C" void kernel_launch(void* const* d_in, const int* in_sizes, int n_in,
                              void* d_out, int out_size, void* d_ws, size_t ws_size,
                              hipStream_t stream) {
  const float* d   = (const float*)d_in[0];
  const float* ang = (const float*)d_in[1];
  const int*   idx = (const int*)d_in[2];
  float* out = (float*)d_out;
  const int T = in_sizes[1];

  KC C;
  {
    const double PI = 3.14159265358979323846;
    double zeros[NSPH][NRAD];
    double prev[NSPH + NRAD - 1];
    int np_ = NSPH + NRAD - 1;
    for (int i = 0; i < np_; ++i) prev[i] = (i + 1) * PI;
    for (int j = 0; j < NRAD; ++j) zeros[0][j] = prev[j];
    for (int l = 1; l < NSPH; ++l) {
      int nc = np_ - 1;
      double cur[NSPH + NRAD - 1];
      for (int i = 0; i < nc; ++i) {
        double a = prev[i], b = prev[i + 1];
        double fa = jn_host(l, a);
        for (int it = 0; it < 80; ++it) {
          double m = 0.5 * (a + b);
          double fm = jn_host(l, m);
          if ((fm > 0.0) == (fa > 0.0)) { a = m; fa = fm; } else { b = m; }
        }
        cur[i] = 0.5 * (a + b);
      }
      for (int i = 0; i < nc; ++i) prev[i] = cur[i];
      np_ = nc;
      for (int j = 0; j < NRAD; ++j) zeros[l][j] = prev[j];
    }
    for (int l = 0; l < NSPH; ++l) {
      double yn = sqrt((2.0 * l + 1.0) / (4.0 * PI));
      for (int n = 0; n < NRAD; ++n) {
        int i = l * NRAD + n;
        double z = zeros[l][n];
        C.zf[i]  = (float)z;
        C.izf[i] = (float)(1.0 / z);
        C.nyf[i] = (float)(sqrt(2.0) / fabs(jn_host(l + 1, z)) * yn);
      }
    }
    // series: j_l(a) = a^l * sum_k c_k (a^2)^k ; c_0 = 1/(2l+1)!!,
    // c_k = -c_{k-1} / (2k*(2l+2k+1))
    for (int l = 5; l <= 6; ++l) {
      double dfact = 1.0;
      for (int m = 2 * l + 1; m > 1; m -= 2) dfact *= m;
      double ck = 1.0 / dfact;
      float* sc = (l == 5) ? C.sc5 : C.sc6;
      sc[0] = (float)ck;
      for (int k = 1; k < 7; ++k) {
        ck = -ck / (2.0 * k * (2 * l + 2 * k + 1));
        sc[k] = (float)ck;
      }
    }
  }

  k_fused<<<(T + BLK - 1) / BLK, BLK, 0, stream>>>(d, ang, idx, out, T, C);
}